// Round 1
// baseline (9638.081 us; speedup 1.0000x reference)
//
#include <hip/hip_runtime.h>
#include <math.h>

constexpr int Bz = 1024;
constexpr int C0 = 271;   // input channels
constexpr int Tt = 281;   // time
constexpr int H1 = 128;
constexpr int H2 = 256;
constexpr int NCLS = 1854;
constexpr int ED = 16;
constexpr float BN_INV = 0.9999950000374996f;  // 1/sqrt(1+1e-5)

__device__ __forceinline__ float gelu_f(float v) {
    return 0.5f * v * (1.0f + erff(v * 0.7071067811865475f));
}

// ---------------- prep kernels ----------------

__global__ void softmax_rows_k(const float* __restrict__ a, float* __restrict__ o, int n) {
    __shared__ float red[256];
    const int row = blockIdx.x, tid = threadIdx.x;
    const float* r = a + (size_t)row * n;
    float m = -1e30f;
    for (int i = tid; i < n; i += 256) m = fmaxf(m, r[i]);
    red[tid] = m; __syncthreads();
    for (int s = 128; s > 0; s >>= 1) { if (tid < s) red[tid] = fmaxf(red[tid], red[tid + s]); __syncthreads(); }
    m = red[0]; __syncthreads();
    float acc = 0.f;
    for (int i = tid; i < n; i += 256) acc += expf(r[i] - m);
    red[tid] = acc; __syncthreads();
    for (int s = 128; s > 0; s >>= 1) { if (tid < s) red[tid] += red[tid + s]; __syncthreads(); }
    const float inv = 1.0f / red[0];
    for (int i = tid; i < n; i += 256) o[(size_t)row * n + i] = expf(r[i] - m) * inv;
}

// M[o][c] = sum_i sa_w[o][i] * attnS[i][c]   (M: [H1][C0])
__global__ void gemm_M_k(const float* __restrict__ sa_w, const float* __restrict__ attnS,
                         float* __restrict__ M) {
    int idx = blockIdx.x * 256 + threadIdx.x;
    if (idx >= H1 * C0) return;
    int o = idx / C0, c = idx - o * C0;
    float s = 0.f;
    for (int i = 0; i < C0; ++i) s = fmaf(sa_w[(size_t)o * C0 + i], attnS[(size_t)i * C0 + c], s);
    M[idx] = s;
}

// MsubT[s][c][o] = sum_h subj_w[s][o][h] * M[h][c]
__global__ void msubT_k(const float* __restrict__ subj_w, const float* __restrict__ M,
                        float* __restrict__ MsubT) {
    int idx = blockIdx.x * 256 + threadIdx.x;
    if (idx >= 4 * C0 * H1) return;
    int s = idx / (C0 * H1);
    int r = idx - s * (C0 * H1);
    int c = r / H1, o = r - c * H1;
    const float* wr = subj_w + ((size_t)s * H1 + o) * H1;
    float a = 0.f;
    for (int h = 0; h < H1; ++h) a = fmaf(wr[h], M[(size_t)h * C0 + c], a);
    MsubT[idx] = a;
}

// biasS[s][o] = sum_h subj_w[s][o][h]*sa_b[h] + subj_b[s][o]
__global__ void biasS_k(const float* __restrict__ subj_w, const float* __restrict__ sa_b,
                        const float* __restrict__ subj_b, float* __restrict__ biasS) {
    int idx = blockIdx.x * 256 + threadIdx.x;
    if (idx >= 4 * H1) return;
    int s = idx >> 7, o = idx & 127;
    const float* wr = subj_w + ((size_t)s * H1 + o) * H1;
    float a = subj_b[idx];
    for (int h = 0; h < H1; ++h) a = fmaf(wr[h], sa_b[h], a);
    biasS[idx] = a;
}

// wT[(c*K+k)*O + o] = w[o*CIN*K + c*K + k]
__global__ void transpose_w_k(const float* __restrict__ w, float* __restrict__ wT,
                              int O, int CIN, int K) {
    int idx = blockIdx.x * 256 + threadIdx.x;
    if (idx >= O * CIN * K) return;
    int o = idx % O, ck = idx / O;
    wT[idx] = w[(size_t)o * CIN * K + ck];
}

// ---------------- main conv kernel ----------------
// out[b][o][t] = epilogue( sum_{c,k} wT[c][k][o] * x[b][c][t+k-(K-1)/2] )
// epilogue: v=(acc+bias[o])*(gamma[o]*BN_INV)+beta[o]; v+=res; v=gelu(v)
// tile: 128 o x 96 t per block; 192 threads (og 0..15 x tg 0..11), 8o x 8t per thread.

constexpr int CONV_TT = 96;
constexpr int CONV_OT = 128;
constexpr int CONV_CC = 16;
constexpr int CONV_THREADS = 192;

template<int K, bool GELU, bool HASRES>
__global__ __launch_bounds__(192)
void conv1d_k(const float* __restrict__ x, const float* __restrict__ wT,
              const float* __restrict__ bias, const float* __restrict__ gamma,
              const float* __restrict__ beta, const float* __restrict__ res,
              float* __restrict__ out, int CIN, int O,
              const int* __restrict__ sidx, int ws_stride, int bs_stride)
{
    constexpr int XROW  = CONV_TT + K - 1;
    constexpr int XROWP = (XROW + 3) & ~3;
    constexpr int WROW  = K * CONV_OT;
    const int b  = blockIdx.z;
    const int o0 = blockIdx.y * CONV_OT;
    const int t0 = blockIdx.x * CONV_TT;
    const int tid = threadIdx.x;
    const int og = tid / 12;    // 0..15
    const int tg = tid % 12;    // 0..11
    const int tl = tg * 8;

    const float* wb = wT;
    const float* bb = bias;
    if (sidx) { int s = sidx[b]; wb += (size_t)s * ws_stride; bb += (size_t)s * bs_stride; }

    __shared__ __align__(16) float xs[CONV_CC][XROWP];
    __shared__ __align__(16) float wsm[CONV_CC][K][CONV_OT];
    float* wsl = &wsm[0][0][0];

    float acc[8][8];
    #pragma unroll
    for (int i = 0; i < 8; ++i)
        #pragma unroll
        for (int j = 0; j < 8; ++j) acc[i][j] = 0.f;

    const float* xb = x + (size_t)b * CIN * Tt;

    for (int c0 = 0; c0 < CIN; c0 += CONV_CC) {
        __syncthreads();
        for (int idx = tid; idx < CONV_CC * XROWP; idx += CONV_THREADS) {
            int c = idx / XROWP, i = idx - c * XROWP;
            int gc = c0 + c;
            int gt = t0 + i - (K - 1) / 2;
            float v = 0.f;
            if (gc < CIN && (unsigned)gt < (unsigned)Tt) v = xb[(size_t)gc * Tt + gt];
            xs[c][i] = v;
        }
        for (int idx = tid; idx < CONV_CC * WROW; idx += CONV_THREADS) {
            int c = idx / WROW, r = idx - c * WROW;   // r = k*OT + ol
            int gc = c0 + c;
            float v = 0.f;
            if (gc < CIN) {
                int k = r / CONV_OT, ol = r - k * CONV_OT;
                v = wb[((size_t)gc * K + k) * O + o0 + ol];
            }
            wsl[idx] = v;
        }
        __syncthreads();
        #pragma unroll 2
        for (int c = 0; c < CONV_CC; ++c) {
            float xw[8 + K - 1];
            #pragma unroll
            for (int i = 0; i < 8 + K - 1; ++i) xw[i] = xs[c][tl + i];
            #pragma unroll
            for (int k = 0; k < K; ++k) {
                #pragma unroll
                for (int oh = 0; oh < 2; ++oh) {
                    const float4 wv = *(const float4*)&wsm[c][k][og * 8 + oh * 4];
                    const float* wf = (const float*)&wv;
                    #pragma unroll
                    for (int oo = 0; oo < 4; ++oo) {
                        const float wvv = wf[oo];
                        #pragma unroll
                        for (int j = 0; j < 8; ++j)
                            acc[oh * 4 + oo][j] = fmaf(wvv, xw[j + k], acc[oh * 4 + oo][j]);
                    }
                }
            }
        }
    }

    #pragma unroll
    for (int oo = 0; oo < 8; ++oo) {
        const int oc = o0 + og * 8 + oo;
        const float bv = bb[oc];
        const float sc = gamma ? gamma[oc] * BN_INV : 1.0f;
        const float sh = beta  ? beta[oc] : 0.0f;
        const size_t orow = ((size_t)b * O + oc) * Tt;
        #pragma unroll
        for (int j = 0; j < 8; ++j) {
            const int t = t0 + tl + j;
            if (t < Tt) {
                float v = (acc[oo][j] + bv) * sc + sh;
                if (HASRES) v += res[orow + t];
                if (GELU)   v = gelu_f(v);
                out[orow + t] = v;
            }
        }
    }
}

// ---------------- head kernels ----------------

__global__ void pool_k(const float* __restrict__ x, float* __restrict__ pooled) {
    const int b = blockIdx.y;
    const int wv = threadIdx.x >> 6, lane = threadIdx.x & 63;
    const int ch = blockIdx.x * 4 + wv;
    const float* row = x + ((size_t)b * H2 + ch) * Tt;
    float s = 0.f;
    for (int t = lane; t < Tt; t += 64) s += row[t];
    #pragma unroll
    for (int o = 32; o > 0; o >>= 1) s += __shfl_down(s, o, 64);
    if (lane == 0) pooled[(size_t)b * H2 + ch] = s * (1.0f / Tt);
}

__global__ void head1_k(const float* __restrict__ pooled, const float* __restrict__ emb,
                        const int* __restrict__ sidx, const float* __restrict__ w1,
                        const float* __restrict__ b1, float* __restrict__ hout) {
    int idx = blockIdx.x * 256 + threadIdx.x;
    if (idx >= Bz * H1) return;
    int b = idx >> 7, j = idx & 127;
    const float* wr = w1 + (size_t)j * (H2 + ED);
    const float* pr = pooled + (size_t)b * H2;
    float a = b1[j];
    for (int i = 0; i < H2; ++i) a = fmaf(pr[i], wr[i], a);
    const float* er = emb + (size_t)sidx[b] * ED;
    #pragma unroll
    for (int e = 0; e < ED; ++e) a = fmaf(er[e], wr[H2 + e], a);
    hout[idx] = fmaxf(a, 0.f);
}

__global__ __launch_bounds__(256)
void head2_k(const float* __restrict__ h, const float* __restrict__ w2,
             const float* __restrict__ b2, float* __restrict__ out) {
    const int n0 = blockIdx.x * 64;
    const int b0 = blockIdx.y * 16;
    __shared__ float hs[16][128];
    __shared__ float w2s[64][129];
    const int tid = threadIdx.x;
    for (int idx = tid; idx < 16 * 128; idx += 256) {
        int bl = idx >> 7, j = idx & 127;
        hs[bl][j] = h[(size_t)(b0 + bl) * H1 + j];
    }
    for (int idx = tid; idx < 64 * 128; idx += 256) {
        int nl = idx >> 7, j = idx & 127;
        int n = n0 + nl;
        w2s[nl][j] = (n < NCLS) ? w2[(size_t)n * H1 + j] : 0.f;
    }
    __syncthreads();
    const int nl = tid & 63, bg = tid >> 6;
    float acc[4] = {0.f, 0.f, 0.f, 0.f};
    for (int j = 0; j < 128; ++j) {
        const float wv = w2s[nl][j];
        #pragma unroll
        for (int bb = 0; bb < 4; ++bb) acc[bb] = fmaf(wv, hs[bg * 4 + bb][j], acc[bb]);
    }
    const int n = n0 + nl;
    if (n < NCLS) {
        const float bv = b2[n];
        #pragma unroll
        for (int bb = 0; bb < 4; ++bb)
            out[(size_t)(b0 + bg * 4 + bb) * NCLS + n] = acc[bb] + bv;
    }
}

// ---------------- host launch ----------------

extern "C" void kernel_launch(void* const* d_in, const int* in_sizes, int n_in,
                              void* d_out, int out_size, void* d_ws, size_t ws_size,
                              hipStream_t stream) {
    const float* X      = (const float*)d_in[0];
    const int*   sidx   = (const int*)  d_in[1];
    const float* attn   = (const float*)d_in[2];
    const float* sa_w   = (const float*)d_in[3];
    const float* sa_b   = (const float*)d_in[4];
    const float* subj_w = (const float*)d_in[5];
    const float* subj_b = (const float*)d_in[6];
    const float* b1c1w = (const float*)d_in[7];  const float* b1c1b = (const float*)d_in[8];
    const float* b1c2w = (const float*)d_in[9];  const float* b1c2b = (const float*)d_in[10];
    const float* b1g1  = (const float*)d_in[11]; const float* b1be1 = (const float*)d_in[12];
    const float* b1g2  = (const float*)d_in[13]; const float* b1be2 = (const float*)d_in[14];
    const float* b2c1w = (const float*)d_in[15]; const float* b2c1b = (const float*)d_in[16];
    const float* b2c2w = (const float*)d_in[17]; const float* b2c2b = (const float*)d_in[18];
    const float* b2g1  = (const float*)d_in[19]; const float* b2be1 = (const float*)d_in[20];
    const float* b2g2  = (const float*)d_in[21]; const float* b2be2 = (const float*)d_in[22];
    const float* b2skw = (const float*)d_in[23]; const float* b2skb = (const float*)d_in[24];
    const float* b3c1w = (const float*)d_in[25]; const float* b3c1b = (const float*)d_in[26];
    const float* b3c2w = (const float*)d_in[27]; const float* b3c2b = (const float*)d_in[28];
    const float* b3g1  = (const float*)d_in[29]; const float* b3be1 = (const float*)d_in[30];
    const float* b3g2  = (const float*)d_in[31]; const float* b3be2 = (const float*)d_in[32];
    const float* emb   = (const float*)d_in[33];
    const float* hw1   = (const float*)d_in[34]; const float* hb1 = (const float*)d_in[35];
    const float* hw2   = (const float*)d_in[36]; const float* hb2 = (const float*)d_in[37];
    float* out = (float*)d_out;
    (void)in_sizes; (void)n_in; (void)out_size; (void)ws_size;

    char* wsp = (char*)d_ws;
    size_t off = 0;
    auto alloc = [&](size_t n) {
        float* p = (float*)(wsp + off);
        off += ((n * sizeof(float)) + 255) & ~(size_t)255;
        return p;
    };
    float* attnS   = alloc((size_t)C0 * C0);
    float* Mmat    = alloc((size_t)H1 * C0);
    float* MsubT   = alloc((size_t)4 * C0 * H1);
    float* biasS   = alloc((size_t)4 * H1);
    float* wt_b1c1 = alloc((size_t)H1 * H1 * 3);
    float* wt_b1c2 = alloc((size_t)H1 * H1 * 3);
    float* wt_b2c1 = alloc((size_t)H1 * H2 * 3);
    float* wt_b2c2 = alloc((size_t)H2 * H2 * 3);
    float* wt_b3c1 = alloc((size_t)H2 * H2 * 3);
    float* wt_b3c2 = alloc((size_t)H2 * H2 * 3);
    float* wt_skip = alloc((size_t)H1 * H2);
    float* pooled  = alloc((size_t)Bz * H2);
    float* hbuf    = alloc((size_t)Bz * H1);
    const size_t bufsz = (size_t)Bz * H2 * Tt;
    float* bufA = alloc(bufsz);
    float* bufB = alloc(bufsz);
    float* bufC = alloc(bufsz);

    // ---- prep (tiny) ----
    softmax_rows_k<<<C0, 256, 0, stream>>>(attn, attnS, C0);
    gemm_M_k<<<(H1 * C0 + 255) / 256, 256, 0, stream>>>(sa_w, attnS, Mmat);
    msubT_k<<<(4 * C0 * H1 + 255) / 256, 256, 0, stream>>>(subj_w, Mmat, MsubT);
    biasS_k<<<2, 256, 0, stream>>>(subj_w, sa_b, subj_b, biasS);
    transpose_w_k<<<(H1 * H1 * 3 + 255) / 256, 256, 0, stream>>>(b1c1w, wt_b1c1, H1, H1, 3);
    transpose_w_k<<<(H1 * H1 * 3 + 255) / 256, 256, 0, stream>>>(b1c2w, wt_b1c2, H1, H1, 3);
    transpose_w_k<<<(H2 * H1 * 3 + 255) / 256, 256, 0, stream>>>(b2c1w, wt_b2c1, H2, H1, 3);
    transpose_w_k<<<(H2 * H2 * 3 + 255) / 256, 256, 0, stream>>>(b2c2w, wt_b2c2, H2, H2, 3);
    transpose_w_k<<<(H2 * H2 * 3 + 255) / 256, 256, 0, stream>>>(b3c1w, wt_b3c1, H2, H2, 3);
    transpose_w_k<<<(H2 * H2 * 3 + 255) / 256, 256, 0, stream>>>(b3c2w, wt_b3c2, H2, H2, 3);
    transpose_w_k<<<(H2 * H1 + 255) / 256, 256, 0, stream>>>(b2skw, wt_skip, H2, H1, 1);

    dim3 cgrid1(3, 1, Bz);   // O=128
    dim3 cgrid2(3, 2, Bz);   // O=256

    // stage A: fused spatial-attention + subject 1x1   X -> bufA [B,128,T]
    conv1d_k<1, false, false><<<cgrid1, 192, 0, stream>>>(
        X, MsubT, biasS, nullptr, nullptr, nullptr, bufA, C0, H1, sidx, C0 * H1, H1);
    // block1 (128->128, identity skip)
    conv1d_k<3, true, false><<<cgrid1, 192, 0, stream>>>(
        bufA, wt_b1c1, b1c1b, b1g1, b1be1, nullptr, bufB, H1, H1, nullptr, 0, 0);
    conv1d_k<3, true, true><<<cgrid1, 192, 0, stream>>>(
        bufB, wt_b1c2, b1c2b, b1g2, b1be2, bufA, bufC, H1, H1, nullptr, 0, 0);
    // block2 (128->256, 1x1-conv skip)
    conv1d_k<1, false, false><<<cgrid2, 192, 0, stream>>>(
        bufC, wt_skip, b2skb, nullptr, nullptr, nullptr, bufA, H1, H2, nullptr, 0, 0);
    conv1d_k<3, true, false><<<cgrid2, 192, 0, stream>>>(
        bufC, wt_b2c1, b2c1b, b2g1, b2be1, nullptr, bufB, H1, H2, nullptr, 0, 0);
    conv1d_k<3, true, true><<<cgrid2, 192, 0, stream>>>(
        bufB, wt_b2c2, b2c2b, b2g2, b2be2, bufA, bufC, H2, H2, nullptr, 0, 0);
    // block3 (256->256, identity skip)
    conv1d_k<3, true, false><<<cgrid2, 192, 0, stream>>>(
        bufC, wt_b3c1, b3c1b, b3g1, b3be1, nullptr, bufA, H2, H2, nullptr, 0, 0);
    conv1d_k<3, true, true><<<cgrid2, 192, 0, stream>>>(
        bufA, wt_b3c2, b3c2b, b3g2, b3be2, bufC, bufB, H2, H2, nullptr, 0, 0);
    // head
    pool_k<<<dim3(H2 / 4, Bz), 256, 0, stream>>>(bufB, pooled);
    head1_k<<<(Bz * H1 + 255) / 256, 256, 0, stream>>>(pooled, emb, sidx, hw1, hb1, hbuf);
    head2_k<<<dim3((NCLS + 63) / 64, Bz / 16), 256, 0, stream>>>(hbuf, hw2, hb2, out);
}

// Round 2
// 1500.097 us; speedup vs baseline: 6.4250x; 6.4250x over previous
//
#include <hip/hip_runtime.h>
#include <hip/hip_bf16.h>
#include <math.h>

constexpr int Bz = 1024;
constexpr int C0 = 271;   // input channels
constexpr int CP0 = 288;  // padded to 9*32
constexpr int Tt = 281;   // time
constexpr int H1 = 128;
constexpr int H2 = 256;
constexpr int NCLS = 1854;
constexpr int ED = 16;
constexpr float BN_INV = 0.9999950000374996f;  // 1/sqrt(1+1e-5)

typedef __attribute__((ext_vector_type(8))) short s16x8;
typedef __attribute__((ext_vector_type(16))) float f32x16;

__device__ __forceinline__ float gelu_f(float v) {
    return 0.5f * v * (1.0f + erff(v * 0.7071067811865475f));
}
__device__ __forceinline__ float bf2f(short s) {
    return __builtin_bit_cast(float, ((unsigned int)(unsigned short)s) << 16);
}
__device__ __forceinline__ short f2bf(float f) {
    return __builtin_bit_cast(short, __float2bfloat16(f));
}

// ---------------- prep kernels ----------------

__global__ void softmax_rows_k(const float* __restrict__ a, float* __restrict__ o, int n) {
    __shared__ float red[256];
    const int row = blockIdx.x, tid = threadIdx.x;
    const float* r = a + (size_t)row * n;
    float m = -1e30f;
    for (int i = tid; i < n; i += 256) m = fmaxf(m, r[i]);
    red[tid] = m; __syncthreads();
    for (int s = 128; s > 0; s >>= 1) { if (tid < s) red[tid] = fmaxf(red[tid], red[tid + s]); __syncthreads(); }
    m = red[0]; __syncthreads();
    float acc = 0.f;
    for (int i = tid; i < n; i += 256) acc += expf(r[i] - m);
    red[tid] = acc; __syncthreads();
    for (int s = 128; s > 0; s >>= 1) { if (tid < s) red[tid] += red[tid + s]; __syncthreads(); }
    const float inv = 1.0f / red[0];
    for (int i = tid; i < n; i += 256) o[(size_t)row * n + i] = expf(r[i] - m) * inv;
}

// M[o][c] = sum_i sa_w[o][i] * attnS[i][c]   (M: [H1][C0])
__global__ void gemm_M_k(const float* __restrict__ sa_w, const float* __restrict__ attnS,
                         float* __restrict__ M) {
    int idx = blockIdx.x * 256 + threadIdx.x;
    if (idx >= H1 * C0) return;
    int o = idx / C0, c = idx - o * C0;
    float s = 0.f;
    for (int i = 0; i < C0; ++i) s = fmaf(sa_w[(size_t)o * C0 + i], attnS[(size_t)i * C0 + c], s);
    M[idx] = s;
}

// wStageA bf16 [s][cc(9)][o(128)][j(32)] : sum_h subj_w[s][o][h] * M[h][c], c=cc*32+j (0 if c>=271)
__global__ void msubA_k(const float* __restrict__ subj_w, const float* __restrict__ M,
                        short* __restrict__ wA) {
    int idx = blockIdx.x * 256 + threadIdx.x;
    if (idx >= 4 * 9 * 128 * 32) return;
    int j = idx & 31;
    int r = idx >> 5;
    int o = r & 127;
    int r2 = r >> 7;
    int cc = r2 % 9;
    int s = r2 / 9;
    int c = cc * 32 + j;
    float a = 0.f;
    if (c < C0) {
        const float* wr = subj_w + ((size_t)s * 128 + o) * 128;
        for (int h = 0; h < 128; ++h) a = fmaf(wr[h], M[(size_t)h * C0 + c], a);
    }
    wA[idx] = f2bf(a);
}

// biasS[s][o] = sum_h subj_w[s][o][h]*sa_b[h] + subj_b[s][o]   (fp32)
__global__ void biasS_k(const float* __restrict__ subj_w, const float* __restrict__ sa_b,
                        const float* __restrict__ subj_b, float* __restrict__ biasS) {
    int idx = blockIdx.x * 256 + threadIdx.x;
    if (idx >= 4 * H1) return;
    int s = idx >> 7, o = idx & 127;
    const float* wr = subj_w + ((size_t)s * H1 + o) * H1;
    float a = subj_b[idx];
    for (int h = 0; h < H1; ++h) a = fmaf(wr[h], sa_b[h], a);
    biasS[idx] = a;
}

// w[o][cin][k] fp32 -> wPre bf16 [cc][k][o][32], zero-pad c>=CIN
__global__ void wprep_k(const float* __restrict__ w, short* __restrict__ o_,
                        int CIN, int O, int K, int NC) {
    int idx = blockIdx.x * 256 + threadIdx.x;
    int total = NC * K * O * 32;
    if (idx >= total) return;
    int j = idx & 31;
    int r = idx >> 5;
    int o = r % O;
    int r2 = r / O;
    int k = r2 % K;
    int cc = r2 / K;
    int c = cc * 32 + j;
    float v = (c < CIN) ? w[((size_t)o * CIN + c) * K + k] : 0.f;
    o_[idx] = f2bf(v);
}

// X [b][c][t] fp32 -> xT [b][t][288] bf16 (zero pad c>=271)
__global__ void xpose_k(const float* __restrict__ X, short* __restrict__ xT) {
    __shared__ float tile[32][33];
    int b = blockIdx.z;
    int t0 = blockIdx.x * 32, c0 = blockIdx.y * 32;
    int tx = threadIdx.x, ty = threadIdx.y;
    #pragma unroll
    for (int i = 0; i < 4; ++i) {
        int c = c0 + ty + i * 8, t = t0 + tx;
        float v = 0.f;
        if (c < C0 && t < Tt) v = X[((size_t)b * C0 + c) * Tt + t];
        tile[ty + i * 8][tx] = v;
    }
    __syncthreads();
    #pragma unroll
    for (int i = 0; i < 4; ++i) {
        int t = t0 + ty + i * 8, c = c0 + tx;
        if (t < Tt && c < CP0) xT[((size_t)b * Tt + t) * CP0 + c] = f2bf(tile[tx][ty + i * 8]);
    }
}

// ---------------- main conv kernel (bf16 MFMA, channels-last) ----------------
// out[b][t][o] = epi( sum_{c,k} W[o][c][k] * x[b][t+k-PAD][c] )
// per block: 96 t x O_BLK o; per wave 64o x 96t = 6 x mfma_32x32x16 acc tiles.
// LDS rows padded to 40 shorts (80B) for even bank-slot spread on ds_read_b128.

template<int K, int O_BLK, int NWAVE, bool GELU, bool HASRES>
__global__ __launch_bounds__(NWAVE * 64, 2)
void convCL_k(const short* __restrict__ xT, int XC, int NC,
              const short* __restrict__ wPre,
              const float* __restrict__ bias,
              const float* __restrict__ gamma, const float* __restrict__ beta,
              const short* __restrict__ res,
              short* __restrict__ out,
              const int* __restrict__ sidx, int wstride, int bstride)
{
    constexpr int NT    = NWAVE * 64;
    constexpr int PAD   = (K - 1) / 2;
    constexpr int XT    = 96 + K - 1;
    constexpr int WROWS = K * O_BLK;
    constexpr int WSH   = WROWS * 40;
    constexpr int OUTSH = 96 * O_BLK;
    constexpr int SH1   = WSH > OUTSH ? WSH : OUTSH;
    constexpr int XCHUNK = XT * 4;       // 16B chunks of x data
    constexpr int WCHUNK = WROWS * 4;    // 16B chunks of w data
    constexpr int O2 = O_BLK * 2;

    __shared__ __align__(16) short sh1[SH1];
    __shared__ __align__(16) short xs[XT * 40];

    const int t0  = blockIdx.x * 96;
    const int b   = blockIdx.y;
    const int tid = threadIdx.x;
    const int lane = tid & 63, wv = tid >> 6;
    const int l31 = lane & 31, hi = lane >> 5;
    const int owave = wv * 64;

    const short* wb = wPre;
    const float* bb = bias;
    if (sidx) { int s = sidx[b]; wb += (size_t)s * wstride; bb += (size_t)s * bstride; }

    f32x16 acc[2][3];
    #pragma unroll
    for (int i = 0; i < 2; ++i)
        #pragma unroll
        for (int j = 0; j < 3; ++j)
            #pragma unroll
            for (int e = 0; e < 16; ++e) acc[i][j][e] = 0.f;

    const size_t xbase = (size_t)b * Tt * XC;

    for (int cc = 0; cc < NC; ++cc) {
        __syncthreads();
        // stage weights: dense [k][o][32] -> padded rows of 40
        const short* wsrc = wb + (size_t)cc * (WROWS * 32);
        #pragma unroll
        for (int it = 0; it < (WCHUNK + NT - 1) / NT; ++it) {
            int q = it * NT + tid;
            if ((WCHUNK % NT) == 0 || q < WCHUNK) {
                int r = q >> 2, p = q & 3;
                *(int4*)((char*)sh1 + r * 80 + p * 16) = *(const int4*)(wsrc + (size_t)q * 8);
            }
        }
        // stage x rows [t][32c] -> padded rows of 40
        const int cbase = cc * 32;
        #pragma unroll
        for (int it = 0; it < (XCHUNK + NT - 1) / NT; ++it) {
            int q = it * NT + tid;
            if (q < XCHUNK) {
                int r = q >> 2, p = q & 3;
                int gt = t0 + r - PAD;
                int4 v = make_int4(0, 0, 0, 0);
                if ((unsigned)gt < (unsigned)Tt)
                    v = *(const int4*)(xT + xbase + (size_t)gt * XC + cbase + p * 8);
                *(int4*)((char*)xs + r * 80 + p * 16) = v;
            }
        }
        __syncthreads();
        // compute
        #pragma unroll
        for (int k = 0; k < K; ++k) {
            #pragma unroll
            for (int kk = 0; kk < 2; ++kk) {
                s16x8 af[2];
                #pragma unroll
                for (int os = 0; os < 2; ++os)
                    af[os] = *(const s16x8*)((const char*)sh1 +
                              (k * O_BLK + owave + os * 32 + l31) * 80 + kk * 32 + hi * 16);
                #pragma unroll
                for (int ts = 0; ts < 3; ++ts) {
                    s16x8 bfv = *(const s16x8*)((const char*)xs +
                                (ts * 32 + l31 + k) * 80 + kk * 32 + hi * 16);
                    #pragma unroll
                    for (int os = 0; os < 2; ++os)
                        acc[os][ts] = __builtin_amdgcn_mfma_f32_32x32x16_bf16(
                            af[os], bfv, acc[os][ts], 0, 0, 0);
                }
            }
        }
    }

    // epilogue: bias + BN in regs, bf16 into swizzled LDS staging
    __syncthreads();
    #pragma unroll
    for (int os = 0; os < 2; ++os) {
        #pragma unroll
        for (int rq = 0; rq < 4; ++rq) {
            #pragma unroll
            for (int rp = 0; rp < 2; ++rp) {
                const int oc = owave + os * 32 + 8 * rq + rp * 2 + 4 * hi;
                const float b0 = bb[oc];
                const float b1 = bb[oc + 1];
                const float g0 = gamma ? gamma[oc] * BN_INV : 1.f;
                const float g1 = gamma ? gamma[oc + 1] * BN_INV : 1.f;
                const float e0 = beta ? beta[oc] : 0.f;
                const float e1 = beta ? beta[oc + 1] : 0.f;
                const int r0 = rq * 4 + rp * 2;
                #pragma unroll
                for (int ts = 0; ts < 3; ++ts) {
                    float v0 = (acc[os][ts][r0] + b0) * g0 + e0;
                    float v1 = (acc[os][ts][r0 + 1] + b1) * g1 + e1;
                    int tloc = ts * 32 + l31;
                    int byte = tloc * O2 + ((oc * 2) ^ ((tloc & 15) << 4));
                    __hip_bfloat162 pk;
                    pk.x = __float2bfloat16(v0);
                    pk.y = __float2bfloat16(v1);
                    *(__hip_bfloat162*)((char*)sh1 + byte) = pk;
                }
            }
        }
    }
    __syncthreads();

    // store pass: coalesced rows, res-add + gelu in fp32
    constexpr int RCH = O_BLK / 8;
    const size_t obase = (size_t)b * Tt * O_BLK;
    for (int q = tid; q < 96 * RCH; q += NT) {
        int r = q / RCH, cp = q % RCH;
        int gt = t0 + r;
        if (gt >= Tt) continue;
        s16x8 hv = *(const s16x8*)((const char*)sh1 + r * O2 + ((cp * 16) ^ ((r & 15) << 4)));
        s16x8 rv;
        if (HASRES) rv = *(const s16x8*)(res + obase + (size_t)gt * O_BLK + cp * 8);
        s16x8 ov;
        #pragma unroll
        for (int j = 0; j < 8; ++j) {
            float v = bf2f(hv[j]);
            if (HASRES) v += bf2f(rv[j]);
            if (GELU) v = gelu_f(v);
            ov[j] = f2bf(v);
        }
        *(s16x8*)(out + obase + (size_t)gt * O_BLK + cp * 8) = ov;
    }
}

// ---------------- head kernels ----------------

__global__ void poolCL_k(const short* __restrict__ x, float* __restrict__ pooled) {
    const int b = blockIdx.x;
    const int o = threadIdx.x;  // 256
    const short* p = x + (size_t)b * Tt * H2 + o;
    float s = 0.f;
    for (int t = 0; t < Tt; ++t) s += bf2f(p[(size_t)t * H2]);
    pooled[(size_t)b * H2 + o] = s * (1.0f / Tt);
}

__global__ void head1_k(const float* __restrict__ pooled, const float* __restrict__ emb,
                        const int* __restrict__ sidx, const float* __restrict__ w1,
                        const float* __restrict__ b1, float* __restrict__ hout) {
    int idx = blockIdx.x * 256 + threadIdx.x;
    if (idx >= Bz * H1) return;
    int b = idx >> 7, j = idx & 127;
    const float* wr = w1 + (size_t)j * (H2 + ED);
    const float* pr = pooled + (size_t)b * H2;
    float a = b1[j];
    for (int i = 0; i < H2; ++i) a = fmaf(pr[i], wr[i], a);
    const float* er = emb + (size_t)sidx[b] * ED;
    #pragma unroll
    for (int e = 0; e < ED; ++e) a = fmaf(er[e], wr[H2 + e], a);
    hout[idx] = fmaxf(a, 0.f);
}

__global__ __launch_bounds__(256)
void head2_k(const float* __restrict__ h, const float* __restrict__ w2,
             const float* __restrict__ b2, float* __restrict__ out) {
    const int n0 = blockIdx.x * 64;
    const int b0 = blockIdx.y * 16;
    __shared__ float hs[16][128];
    __shared__ float w2s[64][129];
    const int tid = threadIdx.x;
    for (int idx = tid; idx < 16 * 128; idx += 256) {
        int bl = idx >> 7, j = idx & 127;
        hs[bl][j] = h[(size_t)(b0 + bl) * H1 + j];
    }
    for (int idx = tid; idx < 64 * 128; idx += 256) {
        int nl = idx >> 7, j = idx & 127;
        int n = n0 + nl;
        w2s[nl][j] = (n < NCLS) ? w2[(size_t)n * H1 + j] : 0.f;
    }
    __syncthreads();
    const int nl = tid & 63, bg = tid >> 6;
    float acc[4] = {0.f, 0.f, 0.f, 0.f};
    for (int j = 0; j < 128; ++j) {
        const float wv = w2s[nl][j];
        #pragma unroll
        for (int bb = 0; bb < 4; ++bb) acc[bb] = fmaf(wv, hs[bg * 4 + bb][j], acc[bb]);
    }
    const int n = n0 + nl;
    if (n < NCLS) {
        const float bv = b2[n];
        #pragma unroll
        for (int bb = 0; bb < 4; ++bb)
            out[(size_t)(b0 + bg * 4 + bb) * NCLS + n] = acc[bb] + bv;
    }
}

// ---------------- host launch ----------------

extern "C" void kernel_launch(void* const* d_in, const int* in_sizes, int n_in,
                              void* d_out, int out_size, void* d_ws, size_t ws_size,
                              hipStream_t stream) {
    const float* X      = (const float*)d_in[0];
    const int*   sidx   = (const int*)  d_in[1];
    const float* attn   = (const float*)d_in[2];
    const float* sa_w   = (const float*)d_in[3];
    const float* sa_b   = (const float*)d_in[4];
    const float* subj_w = (const float*)d_in[5];
    const float* subj_b = (const float*)d_in[6];
    const float* b1c1w = (const float*)d_in[7];  const float* b1c1b = (const float*)d_in[8];
    const float* b1c2w = (const float*)d_in[9];  const float* b1c2b = (const float*)d_in[10];
    const float* b1g1  = (const float*)d_in[11]; const float* b1be1 = (const float*)d_in[12];
    const float* b1g2  = (const float*)d_in[13]; const float* b1be2 = (const float*)d_in[14];
    const float* b2c1w = (const float*)d_in[15]; const float* b2c1b = (const float*)d_in[16];
    const float* b2c2w = (const float*)d_in[17]; const float* b2c2b = (const float*)d_in[18];
    const float* b2g1  = (const float*)d_in[19]; const float* b2be1 = (const float*)d_in[20];
    const float* b2g2  = (const float*)d_in[21]; const float* b2be2 = (const float*)d_in[22];
    const float* b2skw = (const float*)d_in[23]; const float* b2skb = (const float*)d_in[24];
    const float* b3c1w = (const float*)d_in[25]; const float* b3c1b = (const float*)d_in[26];
    const float* b3c2w = (const float*)d_in[27]; const float* b3c2b = (const float*)d_in[28];
    const float* b3g1  = (const float*)d_in[29]; const float* b3be1 = (const float*)d_in[30];
    const float* b3g2  = (const float*)d_in[31]; const float* b3be2 = (const float*)d_in[32];
    const float* emb   = (const float*)d_in[33];
    const float* hw1   = (const float*)d_in[34]; const float* hb1 = (const float*)d_in[35];
    const float* hw2   = (const float*)d_in[36]; const float* hb2 = (const float*)d_in[37];
    float* out = (float*)d_out;
    (void)in_sizes; (void)n_in; (void)out_size; (void)ws_size;

    char* wsp = (char*)d_ws;
    size_t off = 0;
    auto allocF = [&](size_t n) {
        float* p = (float*)(wsp + off);
        off += ((n * sizeof(float)) + 255) & ~(size_t)255;
        return p;
    };
    auto allocS = [&](size_t n) {
        short* p = (short*)(wsp + off);
        off += ((n * sizeof(short)) + 255) & ~(size_t)255;
        return p;
    };
    float* attnS   = allocF((size_t)C0 * C0);
    float* Mmat    = allocF((size_t)H1 * C0);
    float* biasS   = allocF((size_t)4 * H1);
    float* pooled  = allocF((size_t)Bz * H2);
    float* hbuf    = allocF((size_t)Bz * H1);
    short* wStageA = allocS((size_t)4 * 9 * 128 * 32);
    short* wp_b1c1 = allocS((size_t)4 * 3 * 128 * 32);
    short* wp_b1c2 = allocS((size_t)4 * 3 * 128 * 32);
    short* wp_b2c1 = allocS((size_t)4 * 3 * 256 * 32);
    short* wp_b2c2 = allocS((size_t)8 * 3 * 256 * 32);
    short* wp_b3c1 = allocS((size_t)8 * 3 * 256 * 32);
    short* wp_b3c2 = allocS((size_t)8 * 3 * 256 * 32);
    short* wp_skip = allocS((size_t)4 * 1 * 256 * 32);
    short* xT      = allocS((size_t)Bz * Tt * CP0);
    const size_t bufsz = (size_t)Bz * Tt * H2;
    short* bufA = allocS(bufsz);
    short* bufB = allocS(bufsz);
    short* bufC = allocS(bufsz);

    // ---- prep ----
    softmax_rows_k<<<C0, 256, 0, stream>>>(attn, attnS, C0);
    gemm_M_k<<<(H1 * C0 + 255) / 256, 256, 0, stream>>>(sa_w, attnS, Mmat);
    msubA_k<<<(4 * 9 * 128 * 32 + 255) / 256, 256, 0, stream>>>(subj_w, Mmat, wStageA);
    biasS_k<<<2, 256, 0, stream>>>(subj_w, sa_b, subj_b, biasS);
    wprep_k<<<(4 * 3 * 128 * 32 + 255) / 256, 256, 0, stream>>>(b1c1w, wp_b1c1, 128, 128, 3, 4);
    wprep_k<<<(4 * 3 * 128 * 32 + 255) / 256, 256, 0, stream>>>(b1c2w, wp_b1c2, 128, 128, 3, 4);
    wprep_k<<<(4 * 3 * 256 * 32 + 255) / 256, 256, 0, stream>>>(b2c1w, wp_b2c1, 128, 256, 3, 4);
    wprep_k<<<(8 * 3 * 256 * 32 + 255) / 256, 256, 0, stream>>>(b2c2w, wp_b2c2, 256, 256, 3, 8);
    wprep_k<<<(8 * 3 * 256 * 32 + 255) / 256, 256, 0, stream>>>(b3c1w, wp_b3c1, 256, 256, 3, 8);
    wprep_k<<<(8 * 3 * 256 * 32 + 255) / 256, 256, 0, stream>>>(b3c2w, wp_b3c2, 256, 256, 3, 8);
    wprep_k<<<(4 * 1 * 256 * 32 + 255) / 256, 256, 0, stream>>>(b2skw, wp_skip, 128, 256, 1, 4);
    xpose_k<<<dim3(9, 9, Bz), dim3(32, 8), 0, stream>>>(X, xT);

    dim3 cgrid(3, Bz);

    // stage A: fused spatial-attention + subject 1x1   xT -> bufA [B,T,128]
    convCL_k<1, 128, 2, false, false><<<cgrid, 128, 0, stream>>>(
        xT, CP0, 9, wStageA, biasS, nullptr, nullptr, nullptr, bufA, sidx, 9 * 128 * 32, 128);
    // block1 (128->128, identity skip)
    convCL_k<3, 128, 2, true, false><<<cgrid, 128, 0, stream>>>(
        bufA, 128, 4, wp_b1c1, b1c1b, b1g1, b1be1, nullptr, bufB, nullptr, 0, 0);
    convCL_k<3, 128, 2, true, true><<<cgrid, 128, 0, stream>>>(
        bufB, 128, 4, wp_b1c2, b1c2b, b1g2, b1be2, bufA, bufC, nullptr, 0, 0);
    // block2 (128->256, 1x1-conv skip)
    convCL_k<1, 256, 4, false, false><<<cgrid, 256, 0, stream>>>(
        bufC, 128, 4, wp_skip, b2skb, nullptr, nullptr, nullptr, bufA, nullptr, 0, 0);
    convCL_k<3, 256, 4, true, false><<<cgrid, 256, 0, stream>>>(
        bufC, 128, 4, wp_b2c1, b2c1b, b2g1, b2be1, nullptr, bufB, nullptr, 0, 0);
    convCL_k<3, 256, 4, true, true><<<cgrid, 256, 0, stream>>>(
        bufB, 256, 8, wp_b2c2, b2c2b, b2g2, b2be2, bufA, bufC, nullptr, 0, 0);
    // block3 (256->256, identity skip)
    convCL_k<3, 256, 4, true, false><<<cgrid, 256, 0, stream>>>(
        bufC, 256, 8, wp_b3c1, b3c1b, b3g1, b3be1, nullptr, bufA, nullptr, 0, 0);
    convCL_k<3, 256, 4, true, true><<<cgrid, 256, 0, stream>>>(
        bufA, 256, 8, wp_b3c2, b3c2b, b3g2, b3be2, bufC, bufB, nullptr, 0, 0);
    // head
    poolCL_k<<<Bz, 256, 0, stream>>>(bufB, pooled);
    head1_k<<<(Bz * H1 + 255) / 256, 256, 0, stream>>>(pooled, emb, sidx, hw1, hb1, hbuf);
    head2_k<<<dim3((NCLS + 63) / 64, Bz / 16), 256, 0, stream>>>(hbuf, hw2, hb2, out);
}

// Round 3
// 1332.836 us; speedup vs baseline: 7.2313x; 1.1255x over previous
//
#include <hip/hip_runtime.h>
#include <hip/hip_bf16.h>
#include <math.h>

constexpr int Bz = 1024;
constexpr int C0 = 271;   // input channels
constexpr int CP0 = 288;  // padded to 9*32
constexpr int Tt = 281;   // time
constexpr int TR = 292;   // padded rows per batch: row = t+1; rows 0,282..291 zero
constexpr int H1 = 128;
constexpr int H2 = 256;
constexpr int NCLS = 1854;
constexpr int ED = 16;
constexpr float BN_INV = 0.9999950000374996f;  // 1/sqrt(1+1e-5)

typedef __attribute__((ext_vector_type(8))) short s16x8;
typedef __attribute__((ext_vector_type(16))) float f32x16;

__device__ __forceinline__ float gelu_f(float v) {
    return 0.5f * v * (1.0f + erff(v * 0.7071067811865475f));
}
__device__ __forceinline__ float bf2f(short s) {
    return __builtin_bit_cast(float, ((unsigned int)(unsigned short)s) << 16);
}
__device__ __forceinline__ short f2bf(float f) {
    return __builtin_bit_cast(short, __float2bfloat16(f));
}

typedef unsigned int u32;
typedef const __attribute__((address_space(1))) u32 gu32;
typedef __attribute__((address_space(3))) u32 lu32;

// async global->LDS, 16B per lane; LDS dest = uniform base + lane*16
__device__ __forceinline__ void gl16(const void* g, void* l) {
    __builtin_amdgcn_global_load_lds((gu32*)(uintptr_t)g, (lu32*)(uintptr_t)l, 16, 0, 0);
}
template<int N> __device__ __forceinline__ void waitv() {
    asm volatile("s_waitcnt vmcnt(%0)" :: "i"(N) : "memory");
}
__device__ __forceinline__ void hard_barrier() {
    __builtin_amdgcn_s_barrier();
    __builtin_amdgcn_sched_barrier(0);
}

// ---------------- prep kernels ----------------

__global__ void zrows_k(short* base, int C) {
    const int b = blockIdx.x;
    const int n = 11 * (C / 8);
    for (int i = threadIdx.x; i < n; i += 256) {
        int ri = i / (C / 8), c8 = i - ri * (C / 8);
        int row = (ri == 0) ? 0 : 281 + ri;   // 0, 282..291
        *(int4*)(base + ((size_t)b * TR + row) * C + c8 * 8) = make_int4(0, 0, 0, 0);
    }
}

__global__ void softmax_rows_k(const float* __restrict__ a, float* __restrict__ o, int n) {
    __shared__ float red[256];
    const int row = blockIdx.x, tid = threadIdx.x;
    const float* r = a + (size_t)row * n;
    float m = -1e30f;
    for (int i = tid; i < n; i += 256) m = fmaxf(m, r[i]);
    red[tid] = m; __syncthreads();
    for (int s = 128; s > 0; s >>= 1) { if (tid < s) red[tid] = fmaxf(red[tid], red[tid + s]); __syncthreads(); }
    m = red[0]; __syncthreads();
    float acc = 0.f;
    for (int i = tid; i < n; i += 256) acc += expf(r[i] - m);
    red[tid] = acc; __syncthreads();
    for (int s = 128; s > 0; s >>= 1) { if (tid < s) red[tid] += red[tid + s]; __syncthreads(); }
    const float inv = 1.0f / red[0];
    for (int i = tid; i < n; i += 256) o[(size_t)row * n + i] = expf(r[i] - m) * inv;
}

// M[o][c] = sum_i sa_w[o][i] * attnS[i][c]
__global__ void gemm_M_k(const float* __restrict__ sa_w, const float* __restrict__ attnS,
                         float* __restrict__ M) {
    int idx = blockIdx.x * 256 + threadIdx.x;
    if (idx >= H1 * C0) return;
    int o = idx / C0, c = idx - o * C0;
    float s = 0.f;
    for (int i = 0; i < C0; ++i) s = fmaf(sa_w[(size_t)o * C0 + i], attnS[(size_t)i * C0 + c], s);
    M[idx] = s;
}

// fragment-order weights: chunk r=((cc*K+k)*OB32+ob), kk; lane holds o=ob*32+(l&31),
// c = cc*32 + kk*16 + (l>>5)*8 + j
__global__ void wfrag_k(const float* __restrict__ w, short* __restrict__ out,
                        int CIN, int O, int K, int NC) {
    int idx = blockIdx.x * 256 + threadIdx.x;
    int OB32 = O / 32;
    int total = NC * K * OB32 * 2 * 512;
    if (idx >= total) return;
    int j = idx & 7, lane = (idx >> 3) & 63, kk = (idx >> 9) & 1, r = idx >> 10;
    int ob = r % OB32, r2 = r / OB32;
    int k = r2 % K, cc = r2 / K;
    int o = ob * 32 + (lane & 31);
    int c = cc * 32 + kk * 16 + (lane >> 5) * 8 + j;
    float v = (c < CIN) ? w[((size_t)o * CIN + c) * K + k] : 0.f;
    out[idx] = f2bf(v);
}

// stage-A fused weights in fragment order, per subject: val = sum_h subj_w[s][o][h]*M[h][c]
__global__ void msubA_k(const float* __restrict__ subj_w, const float* __restrict__ M,
                        short* __restrict__ out) {
    int idx = blockIdx.x * 256 + threadIdx.x;
    const int per_s = 9 * 1 * 4 * 2 * 512;   // NC=9,K=1,OB32=4
    if (idx >= 4 * per_s) return;
    int s = idx / per_s, rem = idx % per_s;
    int j = rem & 7, lane = (rem >> 3) & 63, kk = (rem >> 9) & 1, r = rem >> 10;
    int ob = r % 4, cc = r / 4;               // K=1
    int o = ob * 32 + (lane & 31);
    int c = cc * 32 + kk * 16 + (lane >> 5) * 8 + j;
    float a = 0.f;
    if (c < C0) {
        const float* wr = subj_w + ((size_t)s * 128 + o) * 128;
        for (int h = 0; h < 128; ++h) a = fmaf(wr[h], M[(size_t)h * C0 + c], a);
    }
    out[idx] = f2bf(a);
}

__global__ void biasS_k(const float* __restrict__ subj_w, const float* __restrict__ sa_b,
                        const float* __restrict__ subj_b, float* __restrict__ biasS) {
    int idx = blockIdx.x * 256 + threadIdx.x;
    if (idx >= 4 * H1) return;
    int s = idx >> 7, o = idx & 127;
    const float* wr = subj_w + ((size_t)s * H1 + o) * H1;
    float a = subj_b[idx];
    for (int h = 0; h < H1; ++h) a = fmaf(wr[h], sa_b[h], a);
    biasS[idx] = a;
}

// X [b][c][t] fp32 -> xT [b][row=t+1][288] bf16
__global__ void xpose_k(const float* __restrict__ X, short* __restrict__ xT) {
    __shared__ float tile[32][33];
    int b = blockIdx.z;
    int t0 = blockIdx.x * 32, c0 = blockIdx.y * 32;
    int tx = threadIdx.x, ty = threadIdx.y;
    #pragma unroll
    for (int i = 0; i < 4; ++i) {
        int c = c0 + ty + i * 8, t = t0 + tx;
        float v = 0.f;
        if (c < C0 && t < Tt) v = X[((size_t)b * C0 + c) * Tt + t];
        tile[ty + i * 8][tx] = v;
    }
    __syncthreads();
    #pragma unroll
    for (int i = 0; i < 4; ++i) {
        int t = t0 + ty + i * 8, c = c0 + tx;
        if (t < Tt) xT[((size_t)b * TR + t + 1) * CP0 + c] = f2bf(tile[tx][ty + i * 8]);
    }
}

// ---------------- main conv kernel: fragment-order MFMA, full-T blocks ----------------
// Block: NB batches x O_BLK outputs x full T. Waves: NB*NOW*3 (3 t-groups of 96).
// Double-buffered LDS staged purely by global_load_lds; counted vmcnt; 2 s_barrier/cc.

template<int K, int NC, int O_BLK, int NOW, int NB, bool GELU, bool HASRES>
__global__ __launch_bounds__(NOW * NB * 192)
void convMF(const short* __restrict__ xin, int XC,
            const short* __restrict__ wfrag,
            const float* __restrict__ bias,
            const float* __restrict__ gamma, const float* __restrict__ beta,
            const short* __restrict__ res, short* __restrict__ out,
            const int* __restrict__ sidx, int wsub, int bsub)
{
    constexpr int NW     = NOW * NB * 3;
    constexpr int NT     = NW * 64;
    constexpr int OB32   = O_BLK / 32;
    constexpr int PAD    = (K - 1) / 2;
    constexpr int RSTART = 1 - PAD;
    constexpr int A_I    = K * OB32 * 2;        // 1KB chunks per cc
    constexpr int X_I    = 18;                  // 288 rows * 64B / 1KB
    constexpr int TI     = A_I + NB * X_I;
    constexpr int Q      = TI / NW;
    constexpr int R      = TI % NW;
    constexpr int QH     = (R > 0) ? Q + 1 : Q;
    constexpr int ABYTES = A_I * 1024;
    constexpr int X_SLOT = X_I * 1024 + 256;    // slack rows for k-overhang reads
    constexpr int HALF   = ABYTES + NB * X_SLOT;
    constexpr int O2     = O_BLK * 2;

    __shared__ __align__(16) char smem[2 * HALF];

    const int b0   = blockIdx.x * NB;
    const int tid  = threadIdx.x;
    const int lane = tid & 63, wv = tid >> 6;
    const int l31  = lane & 31, hi = lane >> 5;
    const int bqw  = wv / (NOW * 3);
    const int w2   = wv % (NOW * 3);
    const int wvt  = w2 / NOW;          // t-group 0..2
    const int wvo  = w2 % NOW;          // o-group
    const int tg   = wvt * 96;
    const int Sw   = Q + (wv < R ? 1 : 0);

    int subj = sidx ? sidx[b0] : 0;
    const char*  wbase = (const char*)(wfrag + (size_t)subj * wsub);
    const float* bb    = bias + (size_t)subj * bsub;

    f32x16 acc[2][3];
    #pragma unroll
    for (int i = 0; i < 2; ++i)
        #pragma unroll
        for (int j = 0; j < 3; ++j)
            #pragma unroll
            for (int e = 0; e < 16; ++e) acc[i][j][e] = 0.f;

    auto issue = [&](int cc, int pb) {
        char* base = smem + pb * HALF;
        const char* wsrc = wbase + (size_t)cc * (A_I * 1024);
        for (int s = 0; s < Sw; ++s) {
            int i = s * NW + wv;
            if (i < A_I) {
                gl16(wsrc + (size_t)i * 1024 + lane * 16, base + i * 1024);
            } else {
                int xi = i - A_I;
                int bql = xi / X_I, seg = xi - bql * X_I;
                int q = seg * 64 + lane;
                int r = q >> 2, p = q & 3;
                int ps = p ^ ((r >> 1) & 3);
                const char* g = (const char*)xin +
                    (((size_t)(b0 + bql) * TR + (RSTART + r)) * XC + cc * 32) * 2 + ps * 16;
                gl16(g, base + ABYTES + bql * X_SLOT + seg * 1024);
            }
        }
    };

    issue(0, 0);
    int cur = 0;
    for (int cc = 0; cc < NC; ++cc) {
        if (cc + 1 < NC) {
            issue(cc + 1, cur ^ 1);
            if (wv < R) waitv<QH>(); else waitv<Q>();
        } else {
            waitv<0>();
        }
        hard_barrier();

        const char* Ab = smem + cur * HALF;
        const char* Xb = Ab + ABYTES + bqw * X_SLOT;
        #pragma unroll
        for (int k = 0; k < K; ++k) {
            #pragma unroll
            for (int kk = 0; kk < 2; ++kk) {
                s16x8 a0 = *(const s16x8*)(Ab + (((k * OB32 + wvo * 2 + 0) * 2 + kk) << 10) + (lane << 4));
                s16x8 a1 = *(const s16x8*)(Ab + (((k * OB32 + wvo * 2 + 1) * 2 + kk) << 10) + (lane << 4));
                #pragma unroll
                for (int ts = 0; ts < 3; ++ts) {
                    int rl = tg + ts * 32 + l31 + k;
                    s16x8 bv = *(const s16x8*)(Xb + rl * 64 + ((((kk << 1) | hi) ^ ((rl >> 1) & 3)) << 4));
                    acc[0][ts] = __builtin_amdgcn_mfma_f32_32x32x16_bf16(a0, bv, acc[0][ts], 0, 0, 0);
                    acc[1][ts] = __builtin_amdgcn_mfma_f32_32x32x16_bf16(a1, bv, acc[1][ts], 0, 0, 0);
                }
            }
        }
        hard_barrier();
        cur ^= 1;
    }

    // ---------------- epilogue: 3 t-sections through LDS ----------------
    constexpr int RCH = O_BLK / 8;
    for (int g = 0; g < 3; ++g) {
        __syncthreads();
        if (wvt == g) {
            #pragma unroll
            for (int os = 0; os < 2; ++os) {
                #pragma unroll
                for (int rq = 0; rq < 4; ++rq) {
                    #pragma unroll
                    for (int rp = 0; rp < 2; ++rp) {
                        const int oc = wvo * 64 + os * 32 + 8 * rq + rp * 2 + 4 * hi;
                        const float bv0 = bb[oc], bv1 = bb[oc + 1];
                        const float g0 = gamma ? gamma[oc] * BN_INV : 1.f;
                        const float g1 = gamma ? gamma[oc + 1] * BN_INV : 1.f;
                        const float e0 = beta ? beta[oc] : 0.f;
                        const float e1 = beta ? beta[oc + 1] : 0.f;
                        const int r0 = rq * 4 + rp * 2;
                        #pragma unroll
                        for (int ts = 0; ts < 3; ++ts) {
                            float v0 = (acc[os][ts][r0] + bv0) * g0 + e0;
                            float v1 = (acc[os][ts][r0 + 1] + bv1) * g1 + e1;
                            int tl = ts * 32 + l31;
                            int byte = (bqw * 96 + tl) * O2 + ((oc * 2) ^ ((tl & 15) << 4));
                            __hip_bfloat162 pk;
                            pk.x = __float2bfloat16(v0);
                            pk.y = __float2bfloat16(v1);
                            *(__hip_bfloat162*)(smem + byte) = pk;
                        }
                    }
                }
            }
        }
        __syncthreads();
        for (int qq = tid; qq < NB * 96 * RCH; qq += NT) {
            int bql = qq / (96 * RCH), rem = qq - bql * (96 * RCH);
            int r = rem / RCH, cp = rem - r * RCH;
            int t = g * 96 + r;
            if (t >= Tt) continue;
            s16x8 hv = *(const s16x8*)(smem + (bql * 96 + r) * O2 + ((cp * 16) ^ ((r & 15) << 4)));
            size_t orow = ((size_t)(b0 + bql) * TR + t + 1) * O_BLK + cp * 8;
            s16x8 rv;
            if (HASRES) rv = *(const s16x8*)(res + orow);
            s16x8 ov;
            #pragma unroll
            for (int j = 0; j < 8; ++j) {
                float v = bf2f(hv[j]);
                if (HASRES) v += bf2f(rv[j]);
                if (GELU) v = gelu_f(v);
                ov[j] = f2bf(v);
            }
            *(s16x8*)(out + orow) = ov;
        }
    }
}

// ---------------- head kernels ----------------

__global__ void poolCL_k(const short* __restrict__ x, float* __restrict__ pooled) {
    const int b = blockIdx.x;
    const int o = threadIdx.x;  // 256
    const short* p = x + ((size_t)b * TR + 1) * H2 + o;
    float s = 0.f;
    for (int t = 0; t < Tt; ++t) s += bf2f(p[(size_t)t * H2]);
    pooled[(size_t)b * H2 + o] = s * (1.0f / Tt);
}

__global__ void head1_k(const float* __restrict__ pooled, const float* __restrict__ emb,
                        const int* __restrict__ sidx, const float* __restrict__ w1,
                        const float* __restrict__ b1, float* __restrict__ hout) {
    int idx = blockIdx.x * 256 + threadIdx.x;
    if (idx >= Bz * H1) return;
    int b = idx >> 7, j = idx & 127;
    const float* wr = w1 + (size_t)j * (H2 + ED);
    const float* pr = pooled + (size_t)b * H2;
    float a = b1[j];
    for (int i = 0; i < H2; ++i) a = fmaf(pr[i], wr[i], a);
    const float* er = emb + (size_t)sidx[b] * ED;
    #pragma unroll
    for (int e = 0; e < ED; ++e) a = fmaf(er[e], wr[H2 + e], a);
    hout[idx] = fmaxf(a, 0.f);
}

__global__ __launch_bounds__(256)
void head2_k(const float* __restrict__ h, const float* __restrict__ w2,
             const float* __restrict__ b2, float* __restrict__ out) {
    const int n0 = blockIdx.x * 64;
    const int b0 = blockIdx.y * 16;
    __shared__ float hs[16][128];
    __shared__ float w2s[64][129];
    const int tid = threadIdx.x;
    for (int idx = tid; idx < 16 * 128; idx += 256) {
        int bl = idx >> 7, j = idx & 127;
        hs[bl][j] = h[(size_t)(b0 + bl) * H1 + j];
    }
    for (int idx = tid; idx < 64 * 128; idx += 256) {
        int nl = idx >> 7, j = idx & 127;
        int n = n0 + nl;
        w2s[nl][j] = (n < NCLS) ? w2[(size_t)n * H1 + j] : 0.f;
    }
    __syncthreads();
    const int nl = tid & 63, bg = tid >> 6;
    float acc[4] = {0.f, 0.f, 0.f, 0.f};
    for (int j = 0; j < 128; ++j) {
        const float wv = w2s[nl][j];
        #pragma unroll
        for (int bb = 0; bb < 4; ++bb) acc[bb] = fmaf(wv, hs[bg * 4 + bb][j], acc[bb]);
    }
    const int n = n0 + nl;
    if (n < NCLS) {
        const float bv = b2[n];
        #pragma unroll
        for (int bb = 0; bb < 4; ++bb)
            out[(size_t)(b0 + bg * 4 + bb) * NCLS + n] = acc[bb] + bv;
    }
}

// ---------------- host launch ----------------

extern "C" void kernel_launch(void* const* d_in, const int* in_sizes, int n_in,
                              void* d_out, int out_size, void* d_ws, size_t ws_size,
                              hipStream_t stream) {
    const float* X      = (const float*)d_in[0];
    const int*   sidx   = (const int*)  d_in[1];
    const float* attn   = (const float*)d_in[2];
    const float* sa_w   = (const float*)d_in[3];
    const float* sa_b   = (const float*)d_in[4];
    const float* subj_w = (const float*)d_in[5];
    const float* subj_b = (const float*)d_in[6];
    const float* b1c1w = (const float*)d_in[7];  const float* b1c1b = (const float*)d_in[8];
    const float* b1c2w = (const float*)d_in[9];  const float* b1c2b = (const float*)d_in[10];
    const float* b1g1  = (const float*)d_in[11]; const float* b1be1 = (const float*)d_in[12];
    const float* b1g2  = (const float*)d_in[13]; const float* b1be2 = (const float*)d_in[14];
    const float* b2c1w = (const float*)d_in[15]; const float* b2c1b = (const float*)d_in[16];
    const float* b2c2w = (const float*)d_in[17]; const float* b2c2b = (const float*)d_in[18];
    const float* b2g1  = (const float*)d_in[19]; const float* b2be1 = (const float*)d_in[20];
    const float* b2g2  = (const float*)d_in[21]; const float* b2be2 = (const float*)d_in[22];
    const float* b2skw = (const float*)d_in[23]; const float* b2skb = (const float*)d_in[24];
    const float* b3c1w = (const float*)d_in[25]; const float* b3c1b = (const float*)d_in[26];
    const float* b3c2w = (const float*)d_in[27]; const float* b3c2b = (const float*)d_in[28];
    const float* b3g1  = (const float*)d_in[29]; const float* b3be1 = (const float*)d_in[30];
    const float* b3g2  = (const float*)d_in[31]; const float* b3be2 = (const float*)d_in[32];
    const float* emb   = (const float*)d_in[33];
    const float* hw1   = (const float*)d_in[34]; const float* hb1 = (const float*)d_in[35];
    const float* hw2   = (const float*)d_in[36]; const float* hb2 = (const float*)d_in[37];
    float* out = (float*)d_out;
    (void)in_sizes; (void)n_in; (void)out_size; (void)ws_size;

    char* wsp = (char*)d_ws;
    size_t off = 0;
    auto allocF = [&](size_t n) {
        float* p = (float*)(wsp + off);
        off += ((n * sizeof(float)) + 255) & ~(size_t)255;
        return p;
    };
    auto allocS = [&](size_t n) {
        short* p = (short*)(wsp + off);
        off += ((n * sizeof(short)) + 255) & ~(size_t)255;
        return p;
    };
    float* attnS   = allocF((size_t)C0 * C0);
    float* Mmat    = allocF((size_t)H1 * C0);
    float* biasS   = allocF((size_t)4 * H1);
    float* pooled  = allocF((size_t)Bz * H2);
    float* hbuf    = allocF((size_t)Bz * H1);
    short* wStageA = allocS((size_t)4 * 9 * 4 * 2 * 512);     // per-subj 36864
    short* wp_b1c1 = allocS((size_t)4 * 3 * 4 * 2 * 512);
    short* wp_b1c2 = allocS((size_t)4 * 3 * 4 * 2 * 512);
    short* wp_skip = allocS((size_t)4 * 1 * 8 * 2 * 512);
    short* wp_b2c1 = allocS((size_t)4 * 3 * 8 * 2 * 512);
    short* wp_b2c2 = allocS((size_t)8 * 3 * 8 * 2 * 512);
    short* wp_b3c1 = allocS((size_t)8 * 3 * 8 * 2 * 512);
    short* wp_b3c2 = allocS((size_t)8 * 3 * 8 * 2 * 512);
    short* xT   = allocS((size_t)Bz * TR * CP0);
    short* bufP = allocS((size_t)Bz * TR * H1);
    short* bufQ = allocS((size_t)Bz * TR * H1);
    short* bufR = allocS((size_t)Bz * TR * H2);
    short* bufS = allocS((size_t)Bz * TR * H2);

    // ---- zero margin rows ----
    zrows_k<<<Bz, 256, 0, stream>>>(xT, CP0);
    zrows_k<<<Bz, 256, 0, stream>>>(bufP, H1);
    zrows_k<<<Bz, 256, 0, stream>>>(bufQ, H1);
    zrows_k<<<Bz, 256, 0, stream>>>(bufR, H2);
    zrows_k<<<Bz, 256, 0, stream>>>(bufS, H2);

    // ---- prep ----
    softmax_rows_k<<<C0, 256, 0, stream>>>(attn, attnS, C0);
    gemm_M_k<<<(H1 * C0 + 255) / 256, 256, 0, stream>>>(sa_w, attnS, Mmat);
    msubA_k<<<(4 * 36864 + 255) / 256, 256, 0, stream>>>(subj_w, Mmat, wStageA);
    biasS_k<<<2, 256, 0, stream>>>(subj_w, sa_b, subj_b, biasS);
    wfrag_k<<<(4*3*4*2*512 + 255) / 256, 256, 0, stream>>>(b1c1w, wp_b1c1, 128, 128, 3, 4);
    wfrag_k<<<(4*3*4*2*512 + 255) / 256, 256, 0, stream>>>(b1c2w, wp_b1c2, 128, 128, 3, 4);
    wfrag_k<<<(4*1*8*2*512 + 255) / 256, 256, 0, stream>>>(b2skw, wp_skip, 128, 256, 1, 4);
    wfrag_k<<<(4*3*8*2*512 + 255) / 256, 256, 0, stream>>>(b2c1w, wp_b2c1, 128, 256, 3, 4);
    wfrag_k<<<(8*3*8*2*512 + 255) / 256, 256, 0, stream>>>(b2c2w, wp_b2c2, 256, 256, 3, 8);
    wfrag_k<<<(8*3*8*2*512 + 255) / 256, 256, 0, stream>>>(b3c1w, wp_b3c1, 256, 256, 3, 8);
    wfrag_k<<<(8*3*8*2*512 + 255) / 256, 256, 0, stream>>>(b3c2w, wp_b3c2, 256, 256, 3, 8);
    xpose_k<<<dim3(9, 9, Bz), dim3(32, 8), 0, stream>>>(X, xT);

    // ---- conv stack ----
    // stageA: xT(288) -> P(128), per-subject weights, bias only
    convMF<1, 9, 128, 2, 1, false, false><<<Bz, 384, 0, stream>>>(
        xT, CP0, wStageA, biasS, nullptr, nullptr, nullptr, bufP, sidx, 36864, 128);
    // block1: P -> Q (gelu+bn); Q (+res P) -> P in-place
    convMF<3, 4, 128, 2, 2, true, false><<<Bz / 2, 768, 0, stream>>>(
        bufP, H1, wp_b1c1, b1c1b, b1g1, b1be1, nullptr, bufQ, nullptr, 0, 0);
    convMF<3, 4, 128, 2, 2, true, true><<<Bz / 2, 768, 0, stream>>>(
        bufQ, H1, wp_b1c2, b1c2b, b1g2, b1be2, bufP, bufP, nullptr, 0, 0);
    // block2: skip P->S; c1 P->R; c2 R(+res S)->S
    convMF<1, 4, 256, 4, 1, false, false><<<Bz, 768, 0, stream>>>(
        bufP, H1, wp_skip, b2skb, nullptr, nullptr, nullptr, bufS, nullptr, 0, 0);
    convMF<3, 4, 256, 4, 1, true, false><<<Bz, 768, 0, stream>>>(
        bufP, H1, wp_b2c1, b2c1b, b2g1, b2be1, nullptr, bufR, nullptr, 0, 0);
    convMF<3, 8, 256, 4, 1, true, true><<<Bz, 768, 0, stream>>>(
        bufR, H2, wp_b2c2, b2c2b, b2g2, b2be2, bufS, bufS, nullptr, 0, 0);
    // block3: c1 S->R; c2 R(+res S)->S
    convMF<3, 8, 256, 4, 1, true, false><<<Bz, 768, 0, stream>>>(
        bufS, H2, wp_b3c1, b3c1b, b3g1, b3be1, nullptr, bufR, nullptr, 0, 0);
    convMF<3, 8, 256, 4, 1, true, true><<<Bz, 768, 0, stream>>>(
        bufR, H2, wp_b3c2, b3c2b, b3g2, b3be2, bufS, bufS, nullptr, 0, 0);

    // ---- head ----
    poolCL_k<<<Bz, 256, 0, stream>>>(bufS, pooled);
    head1_k<<<(Bz * H1 + 255) / 256, 256, 0, stream>>>(pooled, emb, sidx, hw1, hb1, hbuf);
    head2_k<<<dim3((NCLS + 63) / 64, Bz / 16), 256, 0, stream>>>(hbuf, hw2, hb2, out);
}